// Round 9
// baseline (363.390 us; speedup 1.0000x reference)
//
#include <hip/hip_runtime.h>

// Problem constants
#define B_   8
#define N_   1024
#define C_   1024
#define H_   16
#define P_   64
#define D_   64
#define MKV  1088      // P_ + N_
#define ROWS 8192      // B_*N_

typedef float f32x4 __attribute__((ext_vector_type(4)));
typedef __bf16 bf16x8 __attribute__((ext_vector_type(8)));
typedef unsigned short u16x8 __attribute__((ext_vector_type(8)));
typedef unsigned short u16x4 __attribute__((ext_vector_type(4)));

__device__ __forceinline__ unsigned short f2bf(float f) {
  unsigned u = __float_as_uint(f);
  u += 0x7fffu + ((u >> 16) & 1u);   // round-to-nearest-even
  return (unsigned short)(u >> 16);
}

#define GLDS16(g, l)                                                          \
  __builtin_amdgcn_global_load_lds(                                           \
      (const __attribute__((address_space(1))) void*)(g),                     \
      (__attribute__((address_space(3))) void*)(l), 16, 0, 0)

// ---------------------------------------------------------------------------
__global__ __launch_bounds__(256) void cast_bf16_k(
    const float* __restrict__ in, unsigned short* __restrict__ out, int n8) {
  int i = blockIdx.x * 256 + threadIdx.x;
  if (i >= n8) return;
  const float4 a = ((const float4*)in)[i * 2];
  const float4 c = ((const float4*)in)[i * 2 + 1];
  u16x8 o;
  o[0] = f2bf(a.x); o[1] = f2bf(a.y); o[2] = f2bf(a.z); o[3] = f2bf(a.w);
  o[4] = f2bf(c.x); o[5] = f2bf(c.y); o[6] = f2bf(c.z); o[7] = f2bf(c.w);
  *(u16x8*)(out + (size_t)i * 8) = o;
}

// ---------------------------------------------------------------------------
__global__ __launch_bounds__(256) void ln_bf16(
    const float* __restrict__ x, const float* __restrict__ g,
    const float* __restrict__ b, unsigned short* __restrict__ out) {
  const int row = blockIdx.x, t = threadIdx.x;
  const float4 v = ((const float4*)(x + (size_t)row * 1024))[t];
  float s  = v.x + v.y + v.z + v.w;
  float s2 = v.x * v.x + v.y * v.y + v.z * v.z + v.w * v.w;
#pragma unroll
  for (int m = 1; m < 64; m <<= 1) {
    s  += __shfl_xor(s, m);
    s2 += __shfl_xor(s2, m);
  }
  __shared__ float red[8];
  if ((t & 63) == 0) { red[t >> 6] = s; red[4 + (t >> 6)] = s2; }
  __syncthreads();
  s  = red[0] + red[1] + red[2] + red[3];
  s2 = red[4] + red[5] + red[6] + red[7];
  const float mu = s * (1.0f / 1024.0f);
  const float rs = rsqrtf(s2 * (1.0f / 1024.0f) - mu * mu + 1e-5f);
  const float4 gv = ((const float4*)g)[t];
  const float4 bv = ((const float4*)b)[t];
  u16x4 o;
  o[0] = f2bf((v.x - mu) * rs * gv.x + bv.x);
  o[1] = f2bf((v.y - mu) * rs * gv.y + bv.y);
  o[2] = f2bf((v.z - mu) * rs * gv.z + bv.z);
  o[3] = f2bf((v.w - mu) * rs * gv.w + bv.w);
  *(u16x4*)(out + (size_t)row * 1024 + t * 4) = o;
}

// ---------------------------------------------------------------------------
__global__ __launch_bounds__(256) void prefix_fill(
    const float* __restrict__ pk, const float* __restrict__ pv,
    unsigned short* __restrict__ Kb, unsigned short* __restrict__ Vb) {
  int i = blockIdx.x * 256 + threadIdx.x;
  int c8 = i & 127, bp = i >> 7;
  int b = bp >> 6, p = bp & 63;
  int c = c8 << 3, h = c >> 6, d = c & 63;
  size_t sidx = (size_t)bp * 1024 + c;
  size_t didx = (((size_t)(b * 16 + h)) * MKV + p) * 64 + d;
  float4 a = *(const float4*)(pk + sidx);
  float4 a2 = *(const float4*)(pk + sidx + 4);
  u16x8 o;
  o[0] = f2bf(a.x);  o[1] = f2bf(a.y);  o[2] = f2bf(a.z);  o[3] = f2bf(a.w);
  o[4] = f2bf(a2.x); o[5] = f2bf(a2.y); o[6] = f2bf(a2.z); o[7] = f2bf(a2.w);
  *(u16x8*)(Kb + didx) = o;
  a = *(const float4*)(pv + sidx);
  a2 = *(const float4*)(pv + sidx + 4);
  o[0] = f2bf(a.x);  o[1] = f2bf(a.y);  o[2] = f2bf(a.z);  o[3] = f2bf(a.w);
  o[4] = f2bf(a2.x); o[5] = f2bf(a2.y); o[6] = f2bf(a2.z); o[7] = f2bf(a2.w);
  *(u16x8*)(Vb + didx) = o;
}

// ---------------------------------------------------------------------------
__global__ __launch_bounds__(256) void transpose_v(
    const unsigned short* __restrict__ Vb, unsigned short* __restrict__ Vt) {
  __shared__ __align__(16) unsigned short Ts[64 * 66];
  const int kt = blockIdx.x, bh = blockIdx.y;
  const int t = threadIdx.x;
  const unsigned short* src = Vb + ((size_t)bh * MKV + kt * 64) * 64;
#pragma unroll
  for (int rnd = 0; rnd < 2; rnd++) {
    int chunk = rnd * 256 + t;
    int mr = chunk >> 3, d0 = (chunk & 7) << 3;
    u16x8 a = *(const u16x8*)(src + mr * 64 + d0);
#pragma unroll
    for (int j = 0; j < 8; j += 2)
      *(unsigned*)&Ts[mr * 66 + d0 + j] = (unsigned)a[j] | ((unsigned)a[j + 1] << 16);
  }
  __syncthreads();
#pragma unroll
  for (int rnd = 0; rnd < 2; rnd++) {
    int chunk = rnd * 256 + t;
    int dr = chunk >> 3, m0 = (chunk & 7) << 3;
    u16x8 o;
#pragma unroll
    for (int j = 0; j < 8; j++) o[j] = Ts[(m0 + j) * 66 + dr];
    *(u16x8*)(Vt + ((size_t)bh * 64 + dr) * MKV + kt * 64 + m0) = o;
  }
}

// ---------------------------------------------------------------------------
// GEMM "gemm128": C[M,Nd] = A[M,K] @ Bw[Nd,K]^T, bf16 in, fp32 accum.
// m97-class structure per the tile-space evidence (128-tile wins at simple
// 2-barrier loops): BM=BN=128, BK=64 (128B rows -> T2 conflict-free), 256 thr
// (4 waves 2x2, each 64x64), double-buffered 64KB LDS -> 2 blocks/CU, ONE
// __syncthreads per K-tile, NO asm fences/sched_barrier/setprio — compiler
// emits its own fine-grained lgkmcnt pipeline; cross-block overlap (m114)
// hides the barrier drain. Slab XCD swizzle for L2 locality.
template <int EPI>
__global__ __launch_bounds__(256, 2) void gemm128(
    const unsigned short* __restrict__ A, const unsigned short* __restrict__ Bw,
    const float* __restrict__ bias, const float* __restrict__ resid,
    float* __restrict__ outf, unsigned short* __restrict__ outb,
    unsigned short* __restrict__ qout, unsigned short* __restrict__ kout,
    unsigned short* __restrict__ vout, int Ndim, int Kdim) {
  extern __shared__ __align__(16) char smem[];  // A: 2x16KB @0, B: 2x16KB @32768
  const int t = threadIdx.x;
  const int w = t >> 6, l = t & 63;
  const int wr = w >> 1, wc = w & 1;
  const int q4 = l >> 4, r15 = l & 15;
  // XCD slab swizzle (gridDim.x == 64 always): xcd = fid&7 owns 8-bm slab.
  const int fid = (int)blockIdx.y * 64 + blockIdx.x;
  const int bm = (fid & 7) * 8 + ((fid >> 3) & 7);
  const int bn = fid >> 6;
  const int NS = Kdim >> 6;  // K-tiles of 64
  // ---- staging: thread t loads 4 A + 4 B 16B units/tile (pre-swizzled src)
  const int sr = t >> 3;
  const int scb = ((t & 7) << 4) ^ ((sr & 7) << 4);
  const size_t rb = (size_t)Kdim * 2;
  const char* Asrc = (const char*)A + (size_t)(bm * 128 + sr) * rb + scb;
  const char* Bsrc = (const char*)Bw + (size_t)(bn * 128 + sr) * rb + scb;
  char* Ad = smem + t * 16;
  char* Bd = smem + 32768 + t * 16;
#define STG(s_, b_) {                                                         \
    const int ko = (s_) << 7;                                                 \
    GLDS16(Asrc + ko,            Ad + (b_) * 16384);                          \
    GLDS16(Asrc + 32 * rb + ko,  Ad + (b_) * 16384 + 4096);                   \
    GLDS16(Asrc + 64 * rb + ko,  Ad + (b_) * 16384 + 8192);                   \
    GLDS16(Asrc + 96 * rb + ko,  Ad + (b_) * 16384 + 12288);                  \
    GLDS16(Bsrc + ko,            Bd + (b_) * 16384);                          \
    GLDS16(Bsrc + 32 * rb + ko,  Bd + (b_) * 16384 + 4096);                   \
    GLDS16(Bsrc + 64 * rb + ko,  Bd + (b_) * 16384 + 8192);                   \
    GLDS16(Bsrc + 96 * rb + ko,  Bd + (b_) * 16384 + 12288); }
  // ---- fragment read bases (swizzled ds_read)
  const int rx = (r15 & 7) << 4;
  const int c0 = (q4 << 4) ^ rx;
  const int c1 = c0 ^ 64;
  const char* arow = smem + (wr * 64 + r15) * 128;
  const char* brow = smem + 32768 + (wc * 64 + r15) * 128;
  f32x4 acc[4][4] = {};
  STG(0, 0);
  __syncthreads();
  for (int s = 0; s < NS; ++s) {
    if (s + 1 < NS) STG(s + 1, (s + 1) & 1);
    const char* ab = arow + (s & 1) * 16384;
    const char* bb = brow + (s & 1) * 16384;
#pragma unroll
    for (int kk = 0; kk < 2; kk++) {
      const int ck = kk ? c1 : c0;
      bf16x8 af[4], bv[4];
#pragma unroll
      for (int mf = 0; mf < 4; mf++)
        af[mf] = *(const bf16x8*)(ab + mf * 2048 + ck);
#pragma unroll
      for (int nf = 0; nf < 4; nf++)
        bv[nf] = *(const bf16x8*)(bb + nf * 2048 + ck);
#pragma unroll
      for (int mf = 0; mf < 4; mf++)
#pragma unroll
        for (int nf = 0; nf < 4; nf++)
          acc[mf][nf] = __builtin_amdgcn_mfma_f32_16x16x32_bf16(
              af[mf], bv[nf], acc[mf][nf], 0, 0, 0);
    }
    __syncthreads();   // drains vmcnt (next tile staged) + lgkm; joins waves
  }
#undef STG
  // ---- epilogue.  D layout: row=(l>>4)*4+reg, col=l&15 (m89/m91 verified).
  const int orow0 = bm * 128 + wr * 64 + q4 * 4;
  const int ocol0 = bn * 128 + wc * 64 + r15;
  if (EPI == 0) {
    const int which = (bn * 128) >> 10;  // uniform per block (q|k|v)
#pragma unroll
    for (int mi = 0; mi < 4; mi++)
#pragma unroll
      for (int ni = 0; ni < 4; ni++)
#pragma unroll
        for (int r = 0; r < 4; r++) {
          int m = orow0 + mi * 16 + r;
          int c = ocol0 + ni * 16;
          int cc = c & 1023;
          int h = cc >> 6, d = cc & 63;
          int b = m >> 10, n = m & 1023;
          float v = acc[mi][ni][r];
          if (which == 0)   // q, scaled by 1/sqrt(D) * log2(e) for exp2 softmax
            qout[(((size_t)(b * 16 + h)) * 1024 + n) * 64 + d] =
                f2bf(v * 0.18033688f);
          else if (which == 1)
            kout[(((size_t)(b * 16 + h)) * MKV + 64 + n) * 64 + d] = f2bf(v);
          else
            vout[(((size_t)(b * 16 + h)) * MKV + 64 + n) * 64 + d] = f2bf(v);
        }
  } else if (EPI == 1) {
#pragma unroll
    for (int mi = 0; mi < 4; mi++)
#pragma unroll
      for (int ni = 0; ni < 4; ni++)
#pragma unroll
        for (int r = 0; r < 4; r++) {
          int c = ocol0 + ni * 16;
          size_t idx = (size_t)(orow0 + mi * 16 + r) * Ndim + c;
          outf[idx] = resid[idx] + acc[mi][ni][r] + bias[c];
        }
  } else {
#pragma unroll
    for (int mi = 0; mi < 4; mi++)
#pragma unroll
      for (int ni = 0; ni < 4; ni++)
#pragma unroll
        for (int r = 0; r < 4; r++) {
          int c = ocol0 + ni * 16;
          size_t idx = (size_t)(orow0 + mi * 16 + r) * Ndim + c;
          float z = acc[mi][ni][r] + bias[c];
          outb[idx] = f2bf(z / (1.f + __expf(-1.702f * z)));
        }
  }
}

// ---------------------------------------------------------------------------
// Flash attention v4: 4-wave blocks (4 blocks/CU for TLP), exp2-domain
// softmax (log2e folded into q), defer-max (T13, THR=8 log2-units).
// LDS-staged K/V double-buffered (verified R3 structure), swapped QK^T,
// 32 q-rows/wave, grid (bh, qt8).
__device__ __forceinline__ bf16x8 pexch(const unsigned pw[4][2], int kk,
                                        int src0, bool lo) {
  const unsigned a0 = pw[2 * kk][0], a1 = pw[2 * kk][1];
  const unsigned b0 = pw[2 * kk + 1][0], b1 = pw[2 * kk + 1][1];
  unsigned wA0 = (unsigned)__shfl((int)a0, src0);
  unsigned wA1 = (unsigned)__shfl((int)a1, src0);
  unsigned wB0 = (unsigned)__shfl((int)b0, src0);
  unsigned wB1 = (unsigned)__shfl((int)b1, src0);
  unsigned wA0h = (unsigned)__shfl((int)a0, src0 + 16);
  unsigned wA1h = (unsigned)__shfl((int)a1, src0 + 16);
  unsigned wB0h = (unsigned)__shfl((int)b0, src0 + 16);
  unsigned wB1h = (unsigned)__shfl((int)b1, src0 + 16);
  union { unsigned u[4]; bf16x8 v; } pf;
  pf.u[0] = lo ? wA0 : wB0;
  pf.u[1] = lo ? wA1 : wB1;
  pf.u[2] = lo ? wA0h : wB0h;
  pf.u[3] = lo ? wA1h : wB1h;
  return pf.v;
}

__global__ __launch_bounds__(256, 4) void flash_attn(
    const unsigned short* __restrict__ Qb, const unsigned short* __restrict__ Kb,
    const unsigned short* __restrict__ Vt, unsigned short* __restrict__ Ob) {
  __shared__ __align__(16) unsigned short KT[2][4096];
  __shared__ __align__(16) unsigned short VT[2][4096];
  const int t = threadIdx.x;
  const int w = t >> 6, l = t & 63;
  const int g = l >> 4, r15 = l & 15;
  const int bh = blockIdx.x, qt = blockIdx.y;
  const unsigned short* Kbh = Kb + (size_t)bh * MKV * 64;
  const unsigned short* Vbh = Vt + (size_t)bh * 64 * MKV;
  const int srow = t >> 3;                               // 0..31
  const int scb = ((t & 7) << 4) ^ ((srow & 7) << 4);    // pre-swizzled col
  const char* Ksrc0 = (const char*)Kbh + srow * 128 + scb;
  const char* Vsrc0 = (const char*)Vbh + srow * (MKV * 2) + scb;
  const int qbase = qt * 128 + w * 32;
  const unsigned short* Qr0 = Qb + ((size_t)bh * 1024 + qbase + r15) * 64;
  const bf16x8 qf00 = *(const bf16x8*)(Qr0 + g * 8);
  const bf16x8 qf01 = *(const bf16x8*)(Qr0 + 32 + g * 8);
  const bf16x8 qf10 = *(const bf16x8*)(Qr0 + 16 * 64 + g * 8);
  const bf16x8 qf11 = *(const bf16x8*)(Qr0 + 16 * 64 + 32 + g * 8);
  f32x4 Oa0[4] = {}, Oa1[4] = {};
  float m0 = -1e30f, l0 = 0.f, m1 = -1e30f, l1 = 0.f;
  const int src0 = r15 + ((l & 16) << 1);
  const bool lo = (l < 32);
  const int rx = (r15 & 7) << 4;
  // prologue: stage tile 0 (each thread: 2 K units + 2 V units)
  GLDS16(Ksrc0, &KT[0][t * 8]);
  GLDS16(Ksrc0 + 32 * 128, &KT[0][t * 8 + 2048]);
  GLDS16(Vsrc0, &VT[0][t * 8]);
  GLDS16(Vsrc0 + 32 * (MKV * 2), &VT[0][t * 8 + 2048]);
  __syncthreads();
  int cur = 0;
  for (int kt = 0; kt < 17; ++kt) {
    if (kt < 16) {
      GLDS16(Ksrc0 + (kt + 1) * 8192, &KT[cur ^ 1][t * 8]);
      GLDS16(Ksrc0 + (kt + 1) * 8192 + 32 * 128, &KT[cur ^ 1][t * 8 + 2048]);
      GLDS16(Vsrc0 + (kt + 1) * 128, &VT[cur ^ 1][t * 8]);
      GLDS16(Vsrc0 + (kt + 1) * 128 + 32 * (MKV * 2), &VT[cur ^ 1][t * 8 + 2048]);
    }
    const char* Kl = (const char*)&KT[cur][0];
    const char* Vl = (const char*)&VT[cur][0];
    f32x4 S0[4], S1[4];
#pragma unroll
    for (int jc = 0; jc < 4; jc++) {
      const char* kr = Kl + jc * 2048 + r15 * 128;
      bf16x8 k0 = *(const bf16x8*)(kr + ((g * 16) ^ rx));
      bf16x8 k1 = *(const bf16x8*)(kr + ((64 + g * 16) ^ rx));
      f32x4 a0 = {}, a1 = {};
      a0 = __builtin_amdgcn_mfma_f32_16x16x32_bf16(k0, qf00, a0, 0, 0, 0);
      a0 = __builtin_amdgcn_mfma_f32_16x16x32_bf16(k1, qf01, a0, 0, 0, 0);
      a1 = __builtin_amdgcn_mfma_f32_16x16x32_bf16(k0, qf10, a1, 0, 0, 0);
      a1 = __builtin_amdgcn_mfma_f32_16x16x32_bf16(k1, qf11, a1, 0, 0, 0);
      S0[jc] = a0; S1[jc] = a1;
    }
    // ---- online softmax (log2 domain; S already scaled by log2e via q)
    float mx0 = S0[0][0], mx1 = S1[0][0];
#pragma unroll
    for (int jc = 0; jc < 4; jc++)
#pragma unroll
      for (int r = 0; r < 4; r++) {
        mx0 = fmaxf(mx0, S0[jc][r]);
        mx1 = fmaxf(mx1, S1[jc][r]);
      }
    mx0 = fmaxf(mx0, __shfl_xor(mx0, 16));
    mx0 = fmaxf(mx0, __shfl_xor(mx0, 32));
    mx1 = fmaxf(mx1, __shfl_xor(mx1, 16));
    mx1 = fmaxf(mx1, __shfl_xor(mx1, 32));
    // T13 defer-max: skip rescale unless max grew past THR=8 (P <= 2^8)
    if (__any((mx0 > m0 + 8.f) || (mx1 > m1 + 8.f))) {
      float mn0 = fmaxf(m0, mx0);
      float sc0 = exp2f(m0 - mn0);
      m0 = mn0; l0 *= sc0;
      float mn1 = fmaxf(m1, mx1);
      float sc1 = exp2f(m1 - mn1);
      m1 = mn1; l1 *= sc1;
#pragma unroll
      for (int db = 0; db < 4; db++)
#pragma unroll
        for (int r = 0; r < 4; r++) {
          Oa0[db][r] *= sc0;
          Oa1[db][r] *= sc1;
        }
    }
    float rs0 = 0.f, rs1 = 0.f;
#pragma unroll
    for (int jc = 0; jc < 4; jc++)
#pragma unroll
      for (int r = 0; r < 4; r++) {
        float p0 = exp2f(S0[jc][r] - m0);
        float p1 = exp2f(S1[jc][r] - m1);
        S0[jc][r] = p0; S1[jc][r] = p1;
        rs0 += p0; rs1 += p1;
      }
    rs0 += __shfl_xor(rs0, 16);
    rs0 += __shfl_xor(rs0, 32);
    rs1 += __shfl_xor(rs1, 16);
    rs1 += __shfl_xor(rs1, 32);
    l0 += rs0; l1 += rs1;
    unsigned pw0[4][2], pw1[4][2];
#pragma unroll
    for (int jc = 0; jc < 4; jc++) {
      pw0[jc][0] = (unsigned)f2bf(S0[jc][0]) | ((unsigned)f2bf(S0[jc][1]) << 16);
      pw0[jc][1] = (unsigned)f2bf(S0[jc][2]) | ((unsigned)f2bf(S0[jc][3]) << 16);
      pw1[jc][0] = (unsigned)f2bf(S1[jc][0]) | ((unsigned)f2bf(S1[jc][1]) << 16);
      pw1[jc][1] = (unsigned)f2bf(S1[jc][2]) | ((unsigned)f2bf(S1[jc][3]) << 16);
    }
#pragma unroll
    for (int kk = 0; kk < 2; kk++) {
      bf16x8 pf0 = pexch(pw0, kk, src0, lo);
      bf16x8 pf1 = pexch(pw1, kk, src0, lo);
#pragma unroll
      for (int db = 0; db < 4; db++) {
        bf16x8 va = *(const bf16x8*)(Vl + db * 2048 + r15 * 128 +
                                     ((kk * 64 + g * 16) ^ rx));
        Oa0[db] = __builtin_amdgcn_mfma_f32_16x16x32_bf16(va, pf0, Oa0[db], 0, 0, 0);
        Oa1[db] = __builtin_amdgcn_mfma_f32_16x16x32_bf16(va, pf1, Oa1[db], 0, 0, 0);
      }
    }
    __syncthreads();
    cur ^= 1;
  }
  const int b = bh >> 4, h = bh & 15;
  const float i0 = 1.f / l0, i1 = 1.f / l1;
  const int n0 = qbase + r15;
#pragma unroll
  for (int db = 0; db < 4; db++) {
    u16x4 o;
#pragma unroll
    for (int r = 0; r < 4; r++) o[r] = f2bf(Oa0[db][r] * i0);
    *(u16x4*)(Ob + ((size_t)b * 1024 + n0) * 1024 + h * 64 + db * 16 + g * 4) = o;
#pragma unroll
    for (int r = 0; r < 4; r++) o[r] = f2bf(Oa1[db][r] * i1);
    *(u16x4*)(Ob + ((size_t)b * 1024 + n0 + 16) * 1024 + h * 64 + db * 16 + g * 4) = o;
  }
}

// ---------------------------------------------------------------------------
extern "C" void kernel_launch(void* const* d_in, const int* in_sizes, int n_in,
                              void* d_out, int out_size, void* d_ws, size_t ws_size,
                              hipStream_t stream) {
  const float* x       = (const float*)d_in[0];
  const float* pk      = (const float*)d_in[1];
  const float* pv      = (const float*)d_in[2];
  const float* qkv_w   = (const float*)d_in[3];
  const float* proj_w  = (const float*)d_in[4];
  const float* proj_b  = (const float*)d_in[5];
  const float* ln1_g   = (const float*)d_in[6];
  const float* ln1_b   = (const float*)d_in[7];
  const float* ln2_g   = (const float*)d_in[8];
  const float* ln2_b   = (const float*)d_in[9];
  const float* fc_w    = (const float*)d_in[10];
  const float* fc_b    = (const float*)d_in[11];
  const float* cproj_w = (const float*)d_in[12];
  const float* cproj_b = (const float*)d_in[13];
  float* out = (float*)d_out;
  char* ws = (char*)d_ws;

  unsigned short* qkv_wb   = (unsigned short*)(ws + 0);          // 6291456
  unsigned short* proj_wb  = (unsigned short*)(ws + 6291456);    // 2097152
  unsigned short* fc_wb    = (unsigned short*)(ws + 8388608);    // 8388608
  unsigned short* cproj_wb = (unsigned short*)(ws + 16777216);   // 8388608
  float*          x1       = (float*)(ws + 25165824);            // 33554432
  unsigned short* h1       = (unsigned short*)(ws + 58720256);   // 16777216
  unsigned short* o_b      = h1;                                 // alias (h1 dead)
  unsigned short* h2       = (unsigned short*)(ws + 75497472);   // 16777216
  unsigned short* q_buf    = (unsigned short*)(ws + 92274688);   // 16777216
  unsigned short* Kb       = (unsigned short*)(ws + 109051904);  // 17825792
  unsigned short* Vb       = (unsigned short*)(ws + 126877696);  // 17825792
  unsigned short* Vt       = (unsigned short*)(ws + 144703488);  // 17825792
  unsigned short* h3       = (unsigned short*)(ws + 92274688);   // alias (dead)
  if (ws_size < 162529280u) return;

  // allow 64KB dynamic LDS (idempotent host-side calls — capture-safe)
  (void)hipFuncSetAttribute((const void*)gemm128<0>,
      hipFuncAttributeMaxDynamicSharedMemorySize, 65536);
  (void)hipFuncSetAttribute((const void*)gemm128<1>,
      hipFuncAttributeMaxDynamicSharedMemorySize, 65536);
  (void)hipFuncSetAttribute((const void*)gemm128<2>,
      hipFuncAttributeMaxDynamicSharedMemorySize, 65536);

  cast_bf16_k<<<1536, 256, 0, stream>>>(qkv_w, qkv_wb, 393216);
  cast_bf16_k<<<512, 256, 0, stream>>>(proj_w, proj_wb, 131072);
  cast_bf16_k<<<2048, 256, 0, stream>>>(fc_w, fc_wb, 524288);
  cast_bf16_k<<<2048, 256, 0, stream>>>(cproj_w, cproj_wb, 524288);
  ln_bf16<<<ROWS, 256, 0, stream>>>(x, ln1_g, ln1_b, h1);
  prefix_fill<<<256, 256, 0, stream>>>(pk, pv, Kb, Vb);
  gemm128<0><<<dim3(64, 24), 256, 65536, stream>>>(
      h1, qkv_wb, nullptr, nullptr, nullptr, nullptr, q_buf, Kb, Vb, 3072, 1024);
  transpose_v<<<dim3(17, 128), 256, 0, stream>>>(Vb, Vt);
  flash_attn<<<dim3(128, 8), 256, 0, stream>>>(q_buf, Kb, Vt, o_b);
  gemm128<1><<<dim3(64, 8), 256, 65536, stream>>>(
      o_b, proj_wb, proj_b, x, x1, nullptr, nullptr, nullptr, nullptr, 1024, 1024);
  ln_bf16<<<ROWS, 256, 0, stream>>>(x1, ln2_g, ln2_b, h2);
  gemm128<2><<<dim3(64, 32), 256, 65536, stream>>>(
      h2, fc_wb, fc_b, nullptr, nullptr, h3, nullptr, nullptr, nullptr, 4096, 1024);
  gemm128<1><<<dim3(64, 8), 256, 65536, stream>>>(
      h3, cproj_wb, cproj_b, x1, out, nullptr, nullptr, nullptr, nullptr, 1024, 4096);
}

// Round 10
// 351.138 us; speedup vs baseline: 1.0349x; 1.0349x over previous
//
#include <hip/hip_runtime.h>

// Problem constants
#define B_   8
#define N_   1024
#define C_   1024
#define H_   16
#define P_   64
#define D_   64
#define MKV  1088      // P_ + N_
#define ROWS 8192      // B_*N_

typedef float f32x4 __attribute__((ext_vector_type(4)));
typedef __bf16 bf16x8 __attribute__((ext_vector_type(8)));
typedef unsigned short u16x8 __attribute__((ext_vector_type(8)));
typedef unsigned short u16x4 __attribute__((ext_vector_type(4)));

__device__ __forceinline__ unsigned short f2bf(float f) {
  unsigned u = __float_as_uint(f);
  u += 0x7fffu + ((u >> 16) & 1u);   // round-to-nearest-even
  return (unsigned short)(u >> 16);
}

// T12 primitive: pack 2 f32 -> 1 dword of 2 bf16 (lo=a, hi=b) in ONE VALU op.
__device__ __forceinline__ unsigned cvt_pk_bf16(float a, float b) {
  unsigned r;
  asm("v_cvt_pk_bf16_f32 %0, %1, %2" : "=v"(r) : "v"(a), "v"(b));
  return r;
}

#define GLDS16(g, l)                                                          \
  __builtin_amdgcn_global_load_lds(                                           \
      (const __attribute__((address_space(1))) void*)(g),                     \
      (__attribute__((address_space(3))) void*)(l), 16, 0, 0)

// ---------------------------------------------------------------------------
__global__ __launch_bounds__(256) void cast_bf16_k(
    const float* __restrict__ in, unsigned short* __restrict__ out, int n8) {
  int i = blockIdx.x * 256 + threadIdx.x;
  if (i >= n8) return;
  const float4 a = ((const float4*)in)[i * 2];
  const float4 c = ((const float4*)in)[i * 2 + 1];
  u16x8 o;
  o[0] = f2bf(a.x); o[1] = f2bf(a.y); o[2] = f2bf(a.z); o[3] = f2bf(a.w);
  o[4] = f2bf(c.x); o[5] = f2bf(c.y); o[6] = f2bf(c.z); o[7] = f2bf(c.w);
  *(u16x8*)(out + (size_t)i * 8) = o;
}

// ---------------------------------------------------------------------------
__global__ __launch_bounds__(256) void ln_bf16(
    const float* __restrict__ x, const float* __restrict__ g,
    const float* __restrict__ b, unsigned short* __restrict__ out) {
  const int row = blockIdx.x, t = threadIdx.x;
  const float4 v = ((const float4*)(x + (size_t)row * 1024))[t];
  float s  = v.x + v.y + v.z + v.w;
  float s2 = v.x * v.x + v.y * v.y + v.z * v.z + v.w * v.w;
#pragma unroll
  for (int m = 1; m < 64; m <<= 1) {
    s  += __shfl_xor(s, m);
    s2 += __shfl_xor(s2, m);
  }
  __shared__ float red[8];
  if ((t & 63) == 0) { red[t >> 6] = s; red[4 + (t >> 6)] = s2; }
  __syncthreads();
  s  = red[0] + red[1] + red[2] + red[3];
  s2 = red[4] + red[5] + red[6] + red[7];
  const float mu = s * (1.0f / 1024.0f);
  const float rs = rsqrtf(s2 * (1.0f / 1024.0f) - mu * mu + 1e-5f);
  const float4 gv = ((const float4*)g)[t];
  const float4 bv = ((const float4*)b)[t];
  u16x4 o;
  o[0] = f2bf((v.x - mu) * rs * gv.x + bv.x);
  o[1] = f2bf((v.y - mu) * rs * gv.y + bv.y);
  o[2] = f2bf((v.z - mu) * rs * gv.z + bv.z);
  o[3] = f2bf((v.w - mu) * rs * gv.w + bv.w);
  *(u16x4*)(out + (size_t)row * 1024 + t * 4) = o;
}

// ---------------------------------------------------------------------------
__global__ __launch_bounds__(256) void prefix_fill(
    const float* __restrict__ pk, const float* __restrict__ pv,
    unsigned short* __restrict__ Kb, unsigned short* __restrict__ Vb) {
  int i = blockIdx.x * 256 + threadIdx.x;
  int c8 = i & 127, bp = i >> 7;
  int b = bp >> 6, p = bp & 63;
  int c = c8 << 3, h = c >> 6, d = c & 63;
  size_t sidx = (size_t)bp * 1024 + c;
  size_t didx = (((size_t)(b * 16 + h)) * MKV + p) * 64 + d;
  float4 a = *(const float4*)(pk + sidx);
  float4 a2 = *(const float4*)(pk + sidx + 4);
  u16x8 o;
  o[0] = f2bf(a.x);  o[1] = f2bf(a.y);  o[2] = f2bf(a.z);  o[3] = f2bf(a.w);
  o[4] = f2bf(a2.x); o[5] = f2bf(a2.y); o[6] = f2bf(a2.z); o[7] = f2bf(a2.w);
  *(u16x8*)(Kb + didx) = o;
  a = *(const float4*)(pv + sidx);
  a2 = *(const float4*)(pv + sidx + 4);
  o[0] = f2bf(a.x);  o[1] = f2bf(a.y);  o[2] = f2bf(a.z);  o[3] = f2bf(a.w);
  o[4] = f2bf(a2.x); o[5] = f2bf(a2.y); o[6] = f2bf(a2.z); o[7] = f2bf(a2.w);
  *(u16x8*)(Vb + didx) = o;
}

// ---------------------------------------------------------------------------
__global__ __launch_bounds__(256) void transpose_v(
    const unsigned short* __restrict__ Vb, unsigned short* __restrict__ Vt) {
  __shared__ __align__(16) unsigned short Ts[64 * 66];
  const int kt = blockIdx.x, bh = blockIdx.y;
  const int t = threadIdx.x;
  const unsigned short* src = Vb + ((size_t)bh * MKV + kt * 64) * 64;
#pragma unroll
  for (int rnd = 0; rnd < 2; rnd++) {
    int chunk = rnd * 256 + t;
    int mr = chunk >> 3, d0 = (chunk & 7) << 3;
    u16x8 a = *(const u16x8*)(src + mr * 64 + d0);
#pragma unroll
    for (int j = 0; j < 8; j += 2)
      *(unsigned*)&Ts[mr * 66 + d0 + j] = (unsigned)a[j] | ((unsigned)a[j + 1] << 16);
  }
  __syncthreads();
#pragma unroll
  for (int rnd = 0; rnd < 2; rnd++) {
    int chunk = rnd * 256 + t;
    int dr = chunk >> 3, m0 = (chunk & 7) << 3;
    u16x8 o;
#pragma unroll
    for (int j = 0; j < 8; j++) o[j] = Ts[(m0 + j) * 66 + dr];
    *(u16x8*)(Vt + ((size_t)bh * 64 + dr) * MKV + kt * 64 + m0) = o;
  }
}

// ---------------------------------------------------------------------------
// GEMM "gemm128" (R9-verified): BM=BN=128, BK=64, 4 waves, double-buffered
// 64KB LDS -> 2 blocks/CU, ONE __syncthreads per K-tile, no manual fences —
// compiler pipelines lgkmcnt; cross-block overlap hides the barrier drain.
// T2 swizzle both-sides; slab XCD swizzle.
template <int EPI>
__global__ __launch_bounds__(256, 2) void gemm128(
    const unsigned short* __restrict__ A, const unsigned short* __restrict__ Bw,
    const float* __restrict__ bias, const float* __restrict__ resid,
    float* __restrict__ outf, unsigned short* __restrict__ outb,
    unsigned short* __restrict__ qout, unsigned short* __restrict__ kout,
    unsigned short* __restrict__ vout, int Ndim, int Kdim) {
  extern __shared__ __align__(16) char smem[];  // A: 2x16KB @0, B: 2x16KB @32768
  const int t = threadIdx.x;
  const int w = t >> 6, l = t & 63;
  const int wr = w >> 1, wc = w & 1;
  const int q4 = l >> 4, r15 = l & 15;
  const int fid = (int)blockIdx.y * 64 + blockIdx.x;
  const int bm = (fid & 7) * 8 + ((fid >> 3) & 7);
  const int bn = fid >> 6;
  const int NS = Kdim >> 6;
  const int sr = t >> 3;
  const int scb = ((t & 7) << 4) ^ ((sr & 7) << 4);
  const size_t rb = (size_t)Kdim * 2;
  const char* Asrc = (const char*)A + (size_t)(bm * 128 + sr) * rb + scb;
  const char* Bsrc = (const char*)Bw + (size_t)(bn * 128 + sr) * rb + scb;
  char* Ad = smem + t * 16;
  char* Bd = smem + 32768 + t * 16;
#define STG(s_, b_) {                                                         \
    const int ko = (s_) << 7;                                                 \
    GLDS16(Asrc + ko,            Ad + (b_) * 16384);                          \
    GLDS16(Asrc + 32 * rb + ko,  Ad + (b_) * 16384 + 4096);                   \
    GLDS16(Asrc + 64 * rb + ko,  Ad + (b_) * 16384 + 8192);                   \
    GLDS16(Asrc + 96 * rb + ko,  Ad + (b_) * 16384 + 12288);                  \
    GLDS16(Bsrc + ko,            Bd + (b_) * 16384);                          \
    GLDS16(Bsrc + 32 * rb + ko,  Bd + (b_) * 16384 + 4096);                   \
    GLDS16(Bsrc + 64 * rb + ko,  Bd + (b_) * 16384 + 8192);                   \
    GLDS16(Bsrc + 96 * rb + ko,  Bd + (b_) * 16384 + 12288); }
  const int rx = (r15 & 7) << 4;
  const int c0 = (q4 << 4) ^ rx;
  const int c1 = c0 ^ 64;
  const char* arow = smem + (wr * 64 + r15) * 128;
  const char* brow = smem + 32768 + (wc * 64 + r15) * 128;
  f32x4 acc[4][4] = {};
  STG(0, 0);
  __syncthreads();
  for (int s = 0; s < NS; ++s) {
    if (s + 1 < NS) STG(s + 1, (s + 1) & 1);
    const char* ab = arow + (s & 1) * 16384;
    const char* bb = brow + (s & 1) * 16384;
#pragma unroll
    for (int kk = 0; kk < 2; kk++) {
      const int ck = kk ? c1 : c0;
      bf16x8 af[4], bv[4];
#pragma unroll
      for (int mf = 0; mf < 4; mf++)
        af[mf] = *(const bf16x8*)(ab + mf * 2048 + ck);
#pragma unroll
      for (int nf = 0; nf < 4; nf++)
        bv[nf] = *(const bf16x8*)(bb + nf * 2048 + ck);
#pragma unroll
      for (int mf = 0; mf < 4; mf++)
#pragma unroll
        for (int nf = 0; nf < 4; nf++)
          acc[mf][nf] = __builtin_amdgcn_mfma_f32_16x16x32_bf16(
              af[mf], bv[nf], acc[mf][nf], 0, 0, 0);
    }
    __syncthreads();
  }
#undef STG
  const int orow0 = bm * 128 + wr * 64 + q4 * 4;
  const int ocol0 = bn * 128 + wc * 64 + r15;
  if (EPI == 0) {
    const int which = (bn * 128) >> 10;
#pragma unroll
    for (int mi = 0; mi < 4; mi++)
#pragma unroll
      for (int ni = 0; ni < 4; ni++)
#pragma unroll
        for (int r = 0; r < 4; r++) {
          int m = orow0 + mi * 16 + r;
          int c = ocol0 + ni * 16;
          int cc = c & 1023;
          int h = cc >> 6, d = cc & 63;
          int b = m >> 10, n = m & 1023;
          float v = acc[mi][ni][r];
          if (which == 0)   // q scaled by 1/sqrt(D) * log2(e) for exp2 softmax
            qout[(((size_t)(b * 16 + h)) * 1024 + n) * 64 + d] =
                f2bf(v * 0.18033688f);
          else if (which == 1)
            kout[(((size_t)(b * 16 + h)) * MKV + 64 + n) * 64 + d] = f2bf(v);
          else
            vout[(((size_t)(b * 16 + h)) * MKV + 64 + n) * 64 + d] = f2bf(v);
        }
  } else if (EPI == 1) {
#pragma unroll
    for (int mi = 0; mi < 4; mi++)
#pragma unroll
      for (int ni = 0; ni < 4; ni++)
#pragma unroll
        for (int r = 0; r < 4; r++) {
          int c = ocol0 + ni * 16;
          size_t idx = (size_t)(orow0 + mi * 16 + r) * Ndim + c;
          outf[idx] = resid[idx] + acc[mi][ni][r] + bias[c];
        }
  } else {
#pragma unroll
    for (int mi = 0; mi < 4; mi++)
#pragma unroll
      for (int ni = 0; ni < 4; ni++)
#pragma unroll
        for (int r = 0; r < 4; r++) {
          int c = ocol0 + ni * 16;
          size_t idx = (size_t)(orow0 + mi * 16 + r) * Ndim + c;
          float z = acc[mi][ni][r] + bias[c];
          outb[idx] = f2bf(z / (1.f + __expf(-1.702f * z)));
        }
  }
}

// ---------------------------------------------------------------------------
// Flash attention v5 = R8-verified 8-wave structure + exp2-domain softmax +
// defer-max (both numerically verified in R9) + T12 cvt_pk bf16 packing
// (replaces ~144 VALU/tile/wave of scalar f2bf packing with 16 instructions).
__device__ __forceinline__ bf16x8 pexch(const unsigned pw[4][2], int kk,
                                        int src0, bool lo) {
  const unsigned a0 = pw[2 * kk][0], a1 = pw[2 * kk][1];
  const unsigned b0 = pw[2 * kk + 1][0], b1 = pw[2 * kk + 1][1];
  unsigned wA0 = (unsigned)__shfl((int)a0, src0);
  unsigned wA1 = (unsigned)__shfl((int)a1, src0);
  unsigned wB0 = (unsigned)__shfl((int)b0, src0);
  unsigned wB1 = (unsigned)__shfl((int)b1, src0);
  unsigned wA0h = (unsigned)__shfl((int)a0, src0 + 16);
  unsigned wA1h = (unsigned)__shfl((int)a1, src0 + 16);
  unsigned wB0h = (unsigned)__shfl((int)b0, src0 + 16);
  unsigned wB1h = (unsigned)__shfl((int)b1, src0 + 16);
  union { unsigned u[4]; bf16x8 v; } pf;
  pf.u[0] = lo ? wA0 : wB0;
  pf.u[1] = lo ? wA1 : wB1;
  pf.u[2] = lo ? wA0h : wB0h;
  pf.u[3] = lo ? wA1h : wB1h;
  return pf.v;
}

__global__ __launch_bounds__(512, 4) void flash_attn(
    const unsigned short* __restrict__ Qb, const unsigned short* __restrict__ Kb,
    const unsigned short* __restrict__ Vt, unsigned short* __restrict__ Ob) {
  __shared__ __align__(16) unsigned short KT[2][4096];
  __shared__ __align__(16) unsigned short VT[2][4096];
  const int t = threadIdx.x;
  const int w = t >> 6, l = t & 63;
  const int g = l >> 4, r15 = l & 15;
  const int bh = blockIdx.x, qt = blockIdx.y;
  const unsigned short* Kbh = Kb + (size_t)bh * MKV * 64;
  const unsigned short* Vbh = Vt + (size_t)bh * 64 * MKV;
  const int srow = t >> 3;
  const int scb = ((t & 7) << 4) ^ ((srow & 7) << 4);
  const char* Ksrc0 = (const char*)Kbh + srow * 128 + scb;
  const char* Vsrc0 = (const char*)Vbh + srow * (MKV * 2) + scb;
  const int qbase = qt * 256 + w * 32;
  const unsigned short* Qr0 = Qb + ((size_t)bh * 1024 + qbase + r15) * 64;
  const bf16x8 qf00 = *(const bf16x8*)(Qr0 + g * 8);
  const bf16x8 qf01 = *(const bf16x8*)(Qr0 + 32 + g * 8);
  const bf16x8 qf10 = *(const bf16x8*)(Qr0 + 16 * 64 + g * 8);
  const bf16x8 qf11 = *(const bf16x8*)(Qr0 + 16 * 64 + 32 + g * 8);
  f32x4 Oa0[4] = {}, Oa1[4] = {};
  float m0 = -1e30f, l0 = 0.f, m1 = -1e30f, l1 = 0.f;
  const int src0 = r15 + ((l & 16) << 1);
  const bool lo = (l < 32);
  const int rx = (r15 & 7) << 4;
  GLDS16(Ksrc0, &KT[0][t * 8]);
  GLDS16(Vsrc0, &VT[0][t * 8]);
  __syncthreads();
  int cur = 0;
  for (int kt = 0; kt < 17; ++kt) {
    if (kt < 16) {
      GLDS16(Ksrc0 + (kt + 1) * 8192, &KT[cur ^ 1][t * 8]);
      GLDS16(Vsrc0 + (kt + 1) * 128, &VT[cur ^ 1][t * 8]);
    }
    const char* Kl = (const char*)&KT[cur][0];
    const char* Vl = (const char*)&VT[cur][0];
    f32x4 S0[4], S1[4];
#pragma unroll
    for (int jc = 0; jc < 4; jc++) {
      const char* kr = Kl + jc * 2048 + r15 * 128;
      bf16x8 k0 = *(const bf16x8*)(kr + ((g * 16) ^ rx));
      bf16x8 k1 = *(const bf16x8*)(kr + ((64 + g * 16) ^ rx));
      f32x4 a0 = {}, a1 = {};
      a0 = __builtin_amdgcn_mfma_f32_16x16x32_bf16(k0, qf00, a0, 0, 0, 0);
      a0 = __builtin_amdgcn_mfma_f32_16x16x32_bf16(k1, qf01, a0, 0, 0, 0);
      a1 = __builtin_amdgcn_mfma_f32_16x16x32_bf16(k0, qf10, a1, 0, 0, 0);
      a1 = __builtin_amdgcn_mfma_f32_16x16x32_bf16(k1, qf11, a1, 0, 0, 0);
      S0[jc] = a0; S1[jc] = a1;
    }
    // ---- online softmax (log2 domain; log2e folded into q)
    float mx0 = S0[0][0], mx1 = S1[0][0];
#pragma unroll
    for (int jc = 0; jc < 4; jc++)
#pragma unroll
      for (int r = 0; r < 4; r++) {
        mx0 = fmaxf(mx0, S0[jc][r]);
        mx1 = fmaxf(mx1, S1[jc][r]);
      }
    mx0 = fmaxf(mx0, __shfl_xor(mx0, 16));
    mx0 = fmaxf(mx0, __shfl_xor(mx0, 32));
    mx1 = fmaxf(mx1, __shfl_xor(mx1, 16));
    mx1 = fmaxf(mx1, __shfl_xor(mx1, 32));
    // T13 defer-max: skip rescale unless max grew past THR=8 (P <= 2^8)
    if (__any((mx0 > m0 + 8.f) || (mx1 > m1 + 8.f))) {
      float mn0 = fmaxf(m0, mx0);
      float sc0 = exp2f(m0 - mn0);
      m0 = mn0; l0 *= sc0;
      float mn1 = fmaxf(m1, mx1);
      float sc1 = exp2f(m1 - mn1);
      m1 = mn1; l1 *= sc1;
#pragma unroll
      for (int db = 0; db < 4; db++)
#pragma unroll
        for (int r = 0; r < 4; r++) {
          Oa0[db][r] *= sc0;
          Oa1[db][r] *= sc1;
        }
    }
    float rs0 = 0.f, rs1 = 0.f;
#pragma unroll
    for (int jc = 0; jc < 4; jc++)
#pragma unroll
      for (int r = 0; r < 4; r++) {
        float p0 = exp2f(S0[jc][r] - m0);
        float p1 = exp2f(S1[jc][r] - m1);
        S0[jc][r] = p0; S1[jc][r] = p1;
        rs0 += p0; rs1 += p1;
      }
    rs0 += __shfl_xor(rs0, 16);
    rs0 += __shfl_xor(rs0, 32);
    rs1 += __shfl_xor(rs1, 16);
    rs1 += __shfl_xor(rs1, 32);
    l0 += rs0; l1 += rs1;
    // ---- T12: pack P to bf16 pairs with v_cvt_pk_bf16_f32
    unsigned pw0[4][2], pw1[4][2];
#pragma unroll
    for (int jc = 0; jc < 4; jc++) {
      pw0[jc][0] = cvt_pk_bf16(S0[jc][0], S0[jc][1]);
      pw0[jc][1] = cvt_pk_bf16(S0[jc][2], S0[jc][3]);
      pw1[jc][0] = cvt_pk_bf16(S1[jc][0], S1[jc][1]);
      pw1[jc][1] = cvt_pk_bf16(S1[jc][2], S1[jc][3]);
    }
#pragma unroll
    for (int kk = 0; kk < 2; kk++) {
      bf16x8 pf0 = pexch(pw0, kk, src0, lo);
      bf16x8 pf1 = pexch(pw1, kk, src0, lo);
#pragma unroll
      for (int db = 0; db < 4; db++) {
        bf16x8 va = *(const bf16x8*)(Vl + db * 2048 + r15 * 128 +
                                     ((kk * 64 + g * 16) ^ rx));
        Oa0[db] = __builtin_amdgcn_mfma_f32_16x16x32_bf16(va, pf0, Oa0[db], 0, 0, 0);
        Oa1[db] = __builtin_amdgcn_mfma_f32_16x16x32_bf16(va, pf1, Oa1[db], 0, 0, 0);
      }
    }
    __syncthreads();
    cur ^= 1;
  }
  const int b = bh >> 4, h = bh & 15;
  const float i0 = 1.f / l0, i1 = 1.f / l1;
  const int n0 = qbase + r15;
#pragma unroll
  for (int db = 0; db < 4; db++) {
    u16x4 o;
#pragma unroll
    for (int r = 0; r < 4; r++) o[r] = f2bf(Oa0[db][r] * i0);
    *(u16x4*)(Ob + ((size_t)b * 1024 + n0) * 1024 + h * 64 + db * 16 + g * 4) = o;
#pragma unroll
    for (int r = 0; r < 4; r++) o[r] = f2bf(Oa1[db][r] * i1);
    *(u16x4*)(Ob + ((size_t)b * 1024 + n0 + 16) * 1024 + h * 64 + db * 16 + g * 4) = o;
  }
}

// ---------------------------------------------------------------------------
extern "C" void kernel_launch(void* const* d_in, const int* in_sizes, int n_in,
                              void* d_out, int out_size, void* d_ws, size_t ws_size,
                              hipStream_t stream) {
  const float* x       = (const float*)d_in[0];
  const float* pk      = (const float*)d_in[1];
  const float* pv      = (const float*)d_in[2];
  const float* qkv_w   = (const float*)d_in[3];
  const float* proj_w  = (const float*)d_in[4];
  const float* proj_b  = (const float*)d_in[5];
  const float* ln1_g   = (const float*)d_in[6];
  const float* ln1_b   = (const float*)d_in[7];
  const float* ln2_g   = (const float*)d_in[8];
  const float* ln2_b   = (const float*)d_in[9];
  const float* fc_w    = (const float*)d_in[10];
  const float* fc_b    = (const float*)d_in[11];
  const float* cproj_w = (const float*)d_in[12];
  const float* cproj_b = (const float*)d_in[13];
  float* out = (float*)d_out;
  char* ws = (char*)d_ws;

  unsigned short* qkv_wb   = (unsigned short*)(ws + 0);          // 6291456
  unsigned short* proj_wb  = (unsigned short*)(ws + 6291456);    // 2097152
  unsigned short* fc_wb    = (unsigned short*)(ws + 8388608);    // 8388608
  unsigned short* cproj_wb = (unsigned short*)(ws + 16777216);   // 8388608
  float*          x1       = (float*)(ws + 25165824);            // 33554432
  unsigned short* h1       = (unsigned short*)(ws + 58720256);   // 16777216
  unsigned short* o_b      = h1;                                 // alias (h1 dead)
  unsigned short* h2       = (unsigned short*)(ws + 75497472);   // 16777216
  unsigned short* q_buf    = (unsigned short*)(ws + 92274688);   // 16777216
  unsigned short* Kb       = (unsigned short*)(ws + 109051904);  // 17825792
  unsigned short* Vb       = (unsigned short*)(ws + 126877696);  // 17825792
  unsigned short* Vt       = (unsigned short*)(ws + 144703488);  // 17825792
  unsigned short* h3       = (unsigned short*)(ws + 92274688);   // alias (dead)
  if (ws_size < 162529280u) return;

  // allow 64KB dynamic LDS (idempotent host-side calls — capture-safe)
  (void)hipFuncSetAttribute((const void*)gemm128<0>,
      hipFuncAttributeMaxDynamicSharedMemorySize, 65536);
  (void)hipFuncSetAttribute((const void*)gemm128<1>,
      hipFuncAttributeMaxDynamicSharedMemorySize, 65536);
  (void)hipFuncSetAttribute((const void*)gemm128<2>,
      hipFuncAttributeMaxDynamicSharedMemorySize, 65536);

  cast_bf16_k<<<1536, 256, 0, stream>>>(qkv_w, qkv_wb, 393216);
  cast_bf16_k<<<512, 256, 0, stream>>>(proj_w, proj_wb, 131072);
  cast_bf16_k<<<2048, 256, 0, stream>>>(fc_w, fc_wb, 524288);
  cast_bf16_k<<<2048, 256, 0, stream>>>(cproj_w, cproj_wb, 524288);
  ln_bf16<<<ROWS, 256, 0, stream>>>(x, ln1_g, ln1_b, h1);
  prefix_fill<<<256, 256, 0, stream>>>(pk, pv, Kb, Vb);
  gemm128<0><<<dim3(64, 24), 256, 65536, stream>>>(
      h1, qkv_wb, nullptr, nullptr, nullptr, nullptr, q_buf, Kb, Vb, 3072, 1024);
  transpose_v<<<dim3(17, 128), 256, 0, stream>>>(Vb, Vt);
  flash_attn<<<dim3(128, 4), 512, 0, stream>>>(q_buf, Kb, Vt, o_b);
  gemm128<1><<<dim3(64, 8), 256, 65536, stream>>>(
      o_b, proj_wb, proj_b, x, x1, nullptr, nullptr, nullptr, nullptr, 1024, 1024);
  ln_bf16<<<ROWS, 256, 0, stream>>>(x1, ln2_g, ln2_b, h2);
  gemm128<2><<<dim3(64, 32), 256, 65536, stream>>>(
      h2, fc_wb, fc_b, nullptr, nullptr, h3, nullptr, nullptr, nullptr, 4096, 1024);
  gemm128<1><<<dim3(64, 8), 256, 65536, stream>>>(
      h3, cproj_wb, cproj_b, x1, out, nullptr, nullptr, nullptr, nullptr, 1024, 4096);
}

// Round 12
// 341.966 us; speedup vs baseline: 1.0626x; 1.0268x over previous
//
#include <hip/hip_runtime.h>

// Problem constants
#define B_   8
#define N_   1024
#define C_   1024
#define H_   16
#define P_   64
#define D_   64
#define MKV  1088      // P_ + N_
#define ROWS 8192      // B_*N_

typedef float f32x4 __attribute__((ext_vector_type(4)));
typedef __bf16 bf16x8 __attribute__((ext_vector_type(8)));
typedef unsigned short u16x8 __attribute__((ext_vector_type(8)));
typedef unsigned short u16x4 __attribute__((ext_vector_type(4)));

__device__ __forceinline__ unsigned short f2bf(float f) {
  unsigned u = __float_as_uint(f);
  u += 0x7fffu + ((u >> 16) & 1u);   // round-to-nearest-even
  return (unsigned short)(u >> 16);
}

// T12 primitive: pack 2 f32 -> 1 dword of 2 bf16 (lo=a, hi=b) in ONE VALU op.
__device__ __forceinline__ unsigned cvt_pk_bf16(float a, float b) {
  unsigned r;
  asm("v_cvt_pk_bf16_f32 %0, %1, %2" : "=v"(r) : "v"(a), "v"(b));
  return r;
}

#define GLDS16(g, l)                                                          \
  __builtin_amdgcn_global_load_lds(                                           \
      (const __attribute__((address_space(1))) void*)(g),                     \
      (__attribute__((address_space(3))) void*)(l), 16, 0, 0)

// ---------------------------------------------------------------------------
// Fused weight-cast (qkv/proj/fc/cproj fp32->bf16) + prefix k/v fill.
// One launch replaces 5. Segments by flat group index (8 elems/group):
//   [0,393216) qkv_w | [393216,524288) proj_w | [524288,1048576) fc_w |
//   [1048576,1572864) cproj_w | [1572864,1638400) prefix pk/pv scatter.
__global__ __launch_bounds__(256) void cast_all(
    const float* __restrict__ qkv_w, const float* __restrict__ proj_w,
    const float* __restrict__ fc_w, const float* __restrict__ cproj_w,
    const float* __restrict__ pk, const float* __restrict__ pv,
    unsigned short* __restrict__ qkv_wb, unsigned short* __restrict__ proj_wb,
    unsigned short* __restrict__ fc_wb, unsigned short* __restrict__ cproj_wb,
    unsigned short* __restrict__ Kb, unsigned short* __restrict__ Vb) {
  const int i = blockIdx.x * 256 + threadIdx.x;
  if (i < 1572864) {
    const float* in;
    unsigned short* out;
    int j;
    if (i < 393216)       { in = qkv_w;   out = qkv_wb;   j = i; }
    else if (i < 524288)  { in = proj_w;  out = proj_wb;  j = i - 393216; }
    else if (i < 1048576) { in = fc_w;    out = fc_wb;    j = i - 524288; }
    else                  { in = cproj_w; out = cproj_wb; j = i - 1048576; }
    const float4 a = ((const float4*)in)[j * 2];
    const float4 c = ((const float4*)in)[j * 2 + 1];
    u16x8 o;
    o[0] = f2bf(a.x); o[1] = f2bf(a.y); o[2] = f2bf(a.z); o[3] = f2bf(a.w);
    o[4] = f2bf(c.x); o[5] = f2bf(c.y); o[6] = f2bf(c.z); o[7] = f2bf(c.w);
    *(u16x8*)(out + (size_t)j * 8) = o;
  } else {
    const int i2 = i - 1572864;           // [0, 65536)
    int c8 = i2 & 127, bp = i2 >> 7;
    int b = bp >> 6, p = bp & 63;
    int c = c8 << 3, h = c >> 6, d = c & 63;
    size_t sidx = (size_t)bp * 1024 + c;
    size_t didx = (((size_t)(b * 16 + h)) * MKV + p) * 64 + d;
    float4 a = *(const float4*)(pk + sidx);
    float4 a2 = *(const float4*)(pk + sidx + 4);
    u16x8 o;
    o[0] = f2bf(a.x);  o[1] = f2bf(a.y);  o[2] = f2bf(a.z);  o[3] = f2bf(a.w);
    o[4] = f2bf(a2.x); o[5] = f2bf(a2.y); o[6] = f2bf(a2.z); o[7] = f2bf(a2.w);
    *(u16x8*)(Kb + didx) = o;
    a = *(const float4*)(pv + sidx);
    a2 = *(const float4*)(pv + sidx + 4);
    o[0] = f2bf(a.x);  o[1] = f2bf(a.y);  o[2] = f2bf(a.z);  o[3] = f2bf(a.w);
    o[4] = f2bf(a2.x); o[5] = f2bf(a2.y); o[6] = f2bf(a2.z); o[7] = f2bf(a2.w);
    *(u16x8*)(Vb + didx) = o;
  }
}

// ---------------------------------------------------------------------------
__global__ __launch_bounds__(256) void ln_bf16(
    const float* __restrict__ x, const float* __restrict__ g,
    const float* __restrict__ b, unsigned short* __restrict__ out) {
  const int row = blockIdx.x, t = threadIdx.x;
  const float4 v = ((const float4*)(x + (size_t)row * 1024))[t];
  float s  = v.x + v.y + v.z + v.w;
  float s2 = v.x * v.x + v.y * v.y + v.z * v.z + v.w * v.w;
#pragma unroll
  for (int m = 1; m < 64; m <<= 1) {
    s  += __shfl_xor(s, m);
    s2 += __shfl_xor(s2, m);
  }
  __shared__ float red[8];
  if ((t & 63) == 0) { red[t >> 6] = s; red[4 + (t >> 6)] = s2; }
  __syncthreads();
  s  = red[0] + red[1] + red[2] + red[3];
  s2 = red[4] + red[5] + red[6] + red[7];
  const float mu = s * (1.0f / 1024.0f);
  const float rs = rsqrtf(s2 * (1.0f / 1024.0f) - mu * mu + 1e-5f);
  const float4 gv = ((const float4*)g)[t];
  const float4 bv = ((const float4*)b)[t];
  u16x4 o;
  o[0] = f2bf((v.x - mu) * rs * gv.x + bv.x);
  o[1] = f2bf((v.y - mu) * rs * gv.y + bv.y);
  o[2] = f2bf((v.z - mu) * rs * gv.z + bv.z);
  o[3] = f2bf((v.w - mu) * rs * gv.w + bv.w);
  *(u16x4*)(out + (size_t)row * 1024 + t * 4) = o;
}

// ---------------------------------------------------------------------------
__global__ __launch_bounds__(256) void transpose_v(
    const unsigned short* __restrict__ Vb, unsigned short* __restrict__ Vt) {
  __shared__ __align__(16) unsigned short Ts[64 * 66];
  const int kt = blockIdx.x, bh = blockIdx.y;
  const int t = threadIdx.x;
  const unsigned short* src = Vb + ((size_t)bh * MKV + kt * 64) * 64;
#pragma unroll
  for (int rnd = 0; rnd < 2; rnd++) {
    int chunk = rnd * 256 + t;
    int mr = chunk >> 3, d0 = (chunk & 7) << 3;
    u16x8 a = *(const u16x8*)(src + mr * 64 + d0);
#pragma unroll
    for (int j = 0; j < 8; j += 2)
      *(unsigned*)&Ts[mr * 66 + d0 + j] = (unsigned)a[j] | ((unsigned)a[j + 1] << 16);
  }
  __syncthreads();
#pragma unroll
  for (int rnd = 0; rnd < 2; rnd++) {
    int chunk = rnd * 256 + t;
    int dr = chunk >> 3, m0 = (chunk & 7) << 3;
    u16x8 o;
#pragma unroll
    for (int j = 0; j < 8; j++) o[j] = Ts[(m0 + j) * 66 + dr];
    *(u16x8*)(Vt + ((size_t)bh * 64 + dr) * MKV + kt * 64 + m0) = o;
  }
}

// ---------------------------------------------------------------------------
// GEMM "gemm128" (R9/R10-verified): BM=BN=128, BK=64, 4 waves, double-buffered
// 64KB LDS -> 2 blocks/CU, ONE __syncthreads per K-tile, no manual fences —
// compiler pipelines lgkmcnt; cross-block overlap hides the barrier drain.
// T2 swizzle both-sides; slab XCD swizzle.
template <int EPI>
__global__ __launch_bounds__(256, 2) void gemm128(
    const unsigned short* __restrict__ A, const unsigned short* __restrict__ Bw,
    const float* __restrict__ bias, const float* __restrict__ resid,
    float* __restrict__ outf, unsigned short* __restrict__ outb,
    unsigned short* __restrict__ qout, unsigned short* __restrict__ kout,
    unsigned short* __restrict__ vout, int Ndim, int Kdim) {
  extern __shared__ __align__(16) char smem[];  // A: 2x16KB @0, B: 2x16KB @32768
  const int t = threadIdx.x;
  const int w = t >> 6, l = t & 63;
  const int wr = w >> 1, wc = w & 1;
  const int q4 = l >> 4, r15 = l & 15;
  const int fid = (int)blockIdx.y * 64 + blockIdx.x;
  const int bm = (fid & 7) * 8 + ((fid >> 3) & 7);
  const int bn = fid >> 6;
  const int NS = Kdim >> 6;
  const int sr = t >> 3;
  const int scb = ((t & 7) << 4) ^ ((sr & 7) << 4);
  const size_t rb = (size_t)Kdim * 2;
  const char* Asrc = (const char*)A + (size_t)(bm * 128 + sr) * rb + scb;
  const char* Bsrc = (const char*)Bw + (size_t)(bn * 128 + sr) * rb + scb;
  char* Ad = smem + t * 16;
  char* Bd = smem + 32768 + t * 16;
#define STG(s_, b_) {                                                         \
    const int ko = (s_) << 7;                                                 \
    GLDS16(Asrc + ko,            Ad + (b_) * 16384);                          \
    GLDS16(Asrc + 32 * rb + ko,  Ad + (b_) * 16384 + 4096);                   \
    GLDS16(Asrc + 64 * rb + ko,  Ad + (b_) * 16384 + 8192);                   \
    GLDS16(Asrc + 96 * rb + ko,  Ad + (b_) * 16384 + 12288);                  \
    GLDS16(Bsrc + ko,            Bd + (b_) * 16384);                          \
    GLDS16(Bsrc + 32 * rb + ko,  Bd + (b_) * 16384 + 4096);                   \
    GLDS16(Bsrc + 64 * rb + ko,  Bd + (b_) * 16384 + 8192);                   \
    GLDS16(Bsrc + 96 * rb + ko,  Bd + (b_) * 16384 + 12288); }
  const int rx = (r15 & 7) << 4;
  const int c0 = (q4 << 4) ^ rx;
  const int c1 = c0 ^ 64;
  const char* arow = smem + (wr * 64 + r15) * 128;
  const char* brow = smem + 32768 + (wc * 64 + r15) * 128;
  f32x4 acc[4][4] = {};
  STG(0, 0);
  __syncthreads();
  for (int s = 0; s < NS; ++s) {
    if (s + 1 < NS) STG(s + 1, (s + 1) & 1);
    const char* ab = arow + (s & 1) * 16384;
    const char* bb = brow + (s & 1) * 16384;
#pragma unroll
    for (int kk = 0; kk < 2; kk++) {
      const int ck = kk ? c1 : c0;
      bf16x8 af[4], bv[4];
#pragma unroll
      for (int mf = 0; mf < 4; mf++)
        af[mf] = *(const bf16x8*)(ab + mf * 2048 + ck);
#pragma unroll
      for (int nf = 0; nf < 4; nf++)
        bv[nf] = *(const bf16x8*)(bb + nf * 2048 + ck);
#pragma unroll
      for (int mf = 0; mf < 4; mf++)
#pragma unroll
        for (int nf = 0; nf < 4; nf++)
          acc[mf][nf] = __builtin_amdgcn_mfma_f32_16x16x32_bf16(
              af[mf], bv[nf], acc[mf][nf], 0, 0, 0);
    }
    __syncthreads();
  }
#undef STG
  const int orow0 = bm * 128 + wr * 64 + q4 * 4;
  const int ocol0 = bn * 128 + wc * 64 + r15;
  if (EPI == 0) {
    const int which = (bn * 128) >> 10;
#pragma unroll
    for (int mi = 0; mi < 4; mi++)
#pragma unroll
      for (int ni = 0; ni < 4; ni++)
#pragma unroll
        for (int r = 0; r < 4; r++) {
          int m = orow0 + mi * 16 + r;
          int c = ocol0 + ni * 16;
          int cc = c & 1023;
          int h = cc >> 6, d = cc & 63;
          int b = m >> 10, n = m & 1023;
          float v = acc[mi][ni][r];
          if (which == 0)   // q scaled by 1/sqrt(D) * log2(e) for exp2 softmax
            qout[(((size_t)(b * 16 + h)) * 1024 + n) * 64 + d] =
                f2bf(v * 0.18033688f);
          else if (which == 1)
            kout[(((size_t)(b * 16 + h)) * MKV + 64 + n) * 64 + d] = f2bf(v);
          else
            vout[(((size_t)(b * 16 + h)) * MKV + 64 + n) * 64 + d] = f2bf(v);
        }
  } else if (EPI == 1) {
#pragma unroll
    for (int mi = 0; mi < 4; mi++)
#pragma unroll
      for (int ni = 0; ni < 4; ni++)
#pragma unroll
        for (int r = 0; r < 4; r++) {
          int c = ocol0 + ni * 16;
          size_t idx = (size_t)(orow0 + mi * 16 + r) * Ndim + c;
          outf[idx] = resid[idx] + acc[mi][ni][r] + bias[c];
        }
  } else {
#pragma unroll
    for (int mi = 0; mi < 4; mi++)
#pragma unroll
      for (int ni = 0; ni < 4; ni++)
#pragma unroll
        for (int r = 0; r < 4; r++) {
          int c = ocol0 + ni * 16;
          size_t idx = (size_t)(orow0 + mi * 16 + r) * Ndim + c;
          float z = acc[mi][ni][r] + bias[c];
          outb[idx] = f2bf(z / (1.f + __expf(-1.702f * z)));
        }
  }
}

// ---------------------------------------------------------------------------
// Flash attention v5 (R10-verified): 8-wave, exp2-domain softmax, defer-max,
// cvt_pk bf16 packing, LDS-staged K/V double-buffered, swapped QK^T.
__device__ __forceinline__ bf16x8 pexch(const unsigned pw[4][2], int kk,
                                        int src0, bool lo) {
  const unsigned a0 = pw[2 * kk][0], a1 = pw[2 * kk][1];
  const unsigned b0 = pw[2 * kk + 1][0], b1 = pw[2 * kk + 1][1];
  unsigned wA0 = (unsigned)__shfl((int)a0, src0);
  unsigned wA1 = (unsigned)__shfl((int)a1, src0);
  unsigned wB0 = (unsigned)__shfl((int)b0, src0);
  unsigned wB1 = (unsigned)__shfl((int)b1, src0);
  unsigned wA0h = (unsigned)__shfl((int)a0, src0 + 16);
  unsigned wA1h = (unsigned)__shfl((int)a1, src0 + 16);
  unsigned wB0h = (unsigned)__shfl((int)b0, src0 + 16);
  unsigned wB1h = (unsigned)__shfl((int)b1, src0 + 16);
  union { unsigned u[4]; bf16x8 v; } pf;
  pf.u[0] = lo ? wA0 : wB0;
  pf.u[1] = lo ? wA1 : wB1;
  pf.u[2] = lo ? wA0h : wB0h;
  pf.u[3] = lo ? wA1h : wB1h;
  return pf.v;
}

__global__ __launch_bounds__(512, 4) void flash_attn(
    const unsigned short* __restrict__ Qb, const unsigned short* __restrict__ Kb,
    const unsigned short* __restrict__ Vt, unsigned short* __restrict__ Ob) {
  __shared__ __align__(16) unsigned short KT[2][4096];
  __shared__ __align__(16) unsigned short VT[2][4096];
  const int t = threadIdx.x;
  const int w = t >> 6, l = t & 63;
  const int g = l >> 4, r15 = l & 15;
  const int bh = blockIdx.x, qt = blockIdx.y;
  const unsigned short* Kbh = Kb + (size_t)bh * MKV * 64;
  const unsigned short* Vbh = Vt + (size_t)bh * 64 * MKV;
  const int srow = t >> 3;
  const int scb = ((t & 7) << 4) ^ ((srow & 7) << 4);
  const char* Ksrc0 = (const char*)Kbh + srow * 128 + scb;
  const char* Vsrc0 = (const char*)Vbh + srow * (MKV * 2) + scb;
  const int qbase = qt * 256 + w * 32;
  const unsigned short* Qr0 = Qb + ((size_t)bh * 1024 + qbase + r15) * 64;
  const bf16x8 qf00 = *(const bf16x8*)(Qr0 + g * 8);
  const bf16x8 qf01 = *(const bf16x8*)(Qr0 + 32 + g * 8);
  const bf16x8 qf10 = *(const bf16x8*)(Qr0 + 16 * 64 + g * 8);
  const bf16x8 qf11 = *(const bf16x8*)(Qr0 + 16 * 64 + 32 + g * 8);
  f32x4 Oa0[4] = {}, Oa1[4] = {};
  float m0 = -1e30f, l0 = 0.f, m1 = -1e30f, l1 = 0.f;
  const int src0 = r15 + ((l & 16) << 1);
  const bool lo = (l < 32);
  const int rx = (r15 & 7) << 4;
  GLDS16(Ksrc0, &KT[0][t * 8]);
  GLDS16(Vsrc0, &VT[0][t * 8]);
  __syncthreads();
  int cur = 0;
  for (int kt = 0; kt < 17; ++kt) {
    if (kt < 16) {
      GLDS16(Ksrc0 + (kt + 1) * 8192, &KT[cur ^ 1][t * 8]);
      GLDS16(Vsrc0 + (kt + 1) * 128, &VT[cur ^ 1][t * 8]);
    }
    const char* Kl = (const char*)&KT[cur][0];
    const char* Vl = (const char*)&VT[cur][0];
    f32x4 S0[4], S1[4];
#pragma unroll
    for (int jc = 0; jc < 4; jc++) {
      const char* kr = Kl + jc * 2048 + r15 * 128;
      bf16x8 k0 = *(const bf16x8*)(kr + ((g * 16) ^ rx));
      bf16x8 k1 = *(const bf16x8*)(kr + ((64 + g * 16) ^ rx));
      f32x4 a0 = {}, a1 = {};
      a0 = __builtin_amdgcn_mfma_f32_16x16x32_bf16(k0, qf00, a0, 0, 0, 0);
      a0 = __builtin_amdgcn_mfma_f32_16x16x32_bf16(k1, qf01, a0, 0, 0, 0);
      a1 = __builtin_amdgcn_mfma_f32_16x16x32_bf16(k0, qf10, a1, 0, 0, 0);
      a1 = __builtin_amdgcn_mfma_f32_16x16x32_bf16(k1, qf11, a1, 0, 0, 0);
      S0[jc] = a0; S1[jc] = a1;
    }
    float mx0 = S0[0][0], mx1 = S1[0][0];
#pragma unroll
    for (int jc = 0; jc < 4; jc++)
#pragma unroll
      for (int r = 0; r < 4; r++) {
        mx0 = fmaxf(mx0, S0[jc][r]);
        mx1 = fmaxf(mx1, S1[jc][r]);
      }
    mx0 = fmaxf(mx0, __shfl_xor(mx0, 16));
    mx0 = fmaxf(mx0, __shfl_xor(mx0, 32));
    mx1 = fmaxf(mx1, __shfl_xor(mx1, 16));
    mx1 = fmaxf(mx1, __shfl_xor(mx1, 32));
    if (__any((mx0 > m0 + 8.f) || (mx1 > m1 + 8.f))) {
      float mn0 = fmaxf(m0, mx0);
      float sc0 = exp2f(m0 - mn0);
      m0 = mn0; l0 *= sc0;
      float mn1 = fmaxf(m1, mx1);
      float sc1 = exp2f(m1 - mn1);
      m1 = mn1; l1 *= sc1;
#pragma unroll
      for (int db = 0; db < 4; db++)
#pragma unroll
        for (int r = 0; r < 4; r++) {
          Oa0[db][r] *= sc0;
          Oa1[db][r] *= sc1;
        }
    }
    float rs0 = 0.f, rs1 = 0.f;
#pragma unroll
    for (int jc = 0; jc < 4; jc++)
#pragma unroll
      for (int r = 0; r < 4; r++) {
        float p0 = exp2f(S0[jc][r] - m0);
        float p1 = exp2f(S1[jc][r] - m1);
        S0[jc][r] = p0; S1[jc][r] = p1;
        rs0 += p0; rs1 += p1;
      }
    rs0 += __shfl_xor(rs0, 16);
    rs0 += __shfl_xor(rs0, 32);
    rs1 += __shfl_xor(rs1, 16);
    rs1 += __shfl_xor(rs1, 32);
    l0 += rs0; l1 += rs1;
    unsigned pw0[4][2], pw1[4][2];
#pragma unroll
    for (int jc = 0; jc < 4; jc++) {
      pw0[jc][0] = cvt_pk_bf16(S0[jc][0], S0[jc][1]);
      pw0[jc][1] = cvt_pk_bf16(S0[jc][2], S0[jc][3]);
      pw1[jc][0] = cvt_pk_bf16(S1[jc][0], S1[jc][1]);
      pw1[jc][1] = cvt_pk_bf16(S1[jc][2], S1[jc][3]);
    }
#pragma unroll
    for (int kk = 0; kk < 2; kk++) {
      bf16x8 pf0 = pexch(pw0, kk, src0, lo);
      bf16x8 pf1 = pexch(pw1, kk, src0, lo);
#pragma unroll
      for (int db = 0; db < 4; db++) {
        bf16x8 va = *(const bf16x8*)(Vl + db * 2048 + r15 * 128 +
                                     ((kk * 64 + g * 16) ^ rx));
        Oa0[db] = __builtin_amdgcn_mfma_f32_16x16x32_bf16(va, pf0, Oa0[db], 0, 0, 0);
        Oa1[db] = __builtin_amdgcn_mfma_f32_16x16x32_bf16(va, pf1, Oa1[db], 0, 0, 0);
      }
    }
    __syncthreads();
    cur ^= 1;
  }
  const int b = bh >> 4, h = bh & 15;
  const float i0 = 1.f / l0, i1 = 1.f / l1;
  const int n0 = qbase + r15;
#pragma unroll
  for (int db = 0; db < 4; db++) {
    u16x4 o;
#pragma unroll
    for (int r = 0; r < 4; r++) o[r] = f2bf(Oa0[db][r] * i0);
    *(u16x4*)(Ob + ((size_t)b * 1024 + n0) * 1024 + h * 64 + db * 16 + g * 4) = o;
#pragma unroll
    for (int r = 0; r < 4; r++) o[r] = f2bf(Oa1[db][r] * i1);
    *(u16x4*)(Ob + ((size_t)b * 1024 + n0 + 16) * 1024 + h * 64 + db * 16 + g * 4) = o;
  }
}

// ---------------------------------------------------------------------------
extern "C" void kernel_launch(void* const* d_in, const int* in_sizes, int n_in,
                              void* d_out, int out_size, void* d_ws, size_t ws_size,
                              hipStream_t stream) {
  const float* x       = (const float*)d_in[0];
  const float* pk      = (const float*)d_in[1];
  const float* pv      = (const float*)d_in[2];
  const float* qkv_w   = (const float*)d_in[3];
  const float* proj_w  = (const float*)d_in[4];
  const float* proj_b  = (const float*)d_in[5];
  const float* ln1_g   = (const float*)d_in[6];
  const float* ln1_b   = (const float*)d_in[7];
  const float* ln2_g   = (const float*)d_in[8];
  const float* ln2_b   = (const float*)d_in[9];
  const float* fc_w    = (const float*)d_in[10];
  const float* fc_b    = (const float*)d_in[11];
  const float* cproj_w = (const float*)d_in[12];
  const float* cproj_b = (const float*)d_in[13];
  float* out = (float*)d_out;
  char* ws = (char*)d_ws;

  unsigned short* qkv_wb   = (unsigned short*)(ws + 0);          // 6291456
  unsigned short* proj_wb  = (unsigned short*)(ws + 6291456);    // 2097152
  unsigned short* fc_wb    = (unsigned short*)(ws + 8388608);    // 8388608
  unsigned short* cproj_wb = (unsigned short*)(ws + 16777216);   // 8388608
  float*          x1       = (float*)(ws + 25165824);            // 33554432
  unsigned short* h1       = (unsigned short*)(ws + 58720256);   // 16777216
  unsigned short* o_b      = h1;                                 // alias (h1 dead)
  unsigned short* h2       = (unsigned short*)(ws + 75497472);   // 16777216
  unsigned short* q_buf    = (unsigned short*)(ws + 92274688);   // 16777216
  unsigned short* Kb       = (unsigned short*)(ws + 109051904);  // 17825792
  unsigned short* Vb       = (unsigned short*)(ws + 126877696);  // 17825792
  unsigned short* Vt       = (unsigned short*)(ws + 144703488);  // 17825792
  unsigned short* h3       = (unsigned short*)(ws + 92274688);   // alias (dead)
  if (ws_size < 162529280u) return;

  // allow 64KB dynamic LDS (idempotent host-side calls — capture-safe)
  (void)hipFuncSetAttribute((const void*)gemm128<0>,
      hipFuncAttributeMaxDynamicSharedMemorySize, 65536);
  (void)hipFuncSetAttribute((const void*)gemm128<1>,
      hipFuncAttributeMaxDynamicSharedMemorySize, 65536);
  (void)hipFuncSetAttribute((const void*)gemm128<2>,
      hipFuncAttributeMaxDynamicSharedMemorySize, 65536);

  cast_all<<<6400, 256, 0, stream>>>(qkv_w, proj_w, fc_w, cproj_w, pk, pv,
                                     qkv_wb, proj_wb, fc_wb, cproj_wb, Kb, Vb);
  ln_bf16<<<ROWS, 256, 0, stream>>>(x, ln1_g, ln1_b, h1);
  gemm128<0><<<dim3(64, 24), 256, 65536, stream>>>(
      h1, qkv_wb, nullptr, nullptr, nullptr, nullptr, q_buf, Kb, Vb, 3072, 1024);
  transpose_v<<<dim3(17, 128), 256, 0, stream>>>(Vb, Vt);
  flash_attn<<<dim3(128, 4), 512, 0, stream>>>(q_buf, Kb, Vt, o_b);
  gemm128<1><<<dim3(64, 8), 256, 65536, stream>>>(
      o_b, proj_wb, proj_b, x, x1, nullptr, nullptr, nullptr, nullptr, 1024, 1024);
  ln_bf16<<<ROWS, 256, 0, stream>>>(x1, ln2_g, ln2_b, h2);
  gemm128<2><<<dim3(64, 32), 256, 65536, stream>>>(
      h2, fc_wb, fc_b, nullptr, nullptr, h3, nullptr, nullptr, nullptr, 4096, 1024);
  gemm128<1><<<dim3(64, 8), 256, 65536, stream>>>(
      h3, cproj_wb, cproj_b, x1, out, nullptr, nullptr, nullptr, nullptr, 1024, 4096);
}